// Round 2
// baseline (263.070 us; speedup 1.0000x reference)
//
#include <hip/hip_runtime.h>

#define B_ 16384
#define D_ 2048
#define P_ 64
#define K_ 5

#define BM 64
#define BK 64
#define NCH (D_ / BK)

// ---------------------------------------------------------------------------
// Kernel 1: parent logits GEMM [B,D]x[D,P] + bias, argmax -> pc[], logits out.
// grid 256 blocks x 256 threads; block = 64 rows x 64 parents, full-D loop.
// LDS tiles stored transposed + XOR-swizzled: elem (d, c) at d*64 + (c ^ 4*(d>>2))
// so transpose writes and float4 reads are both ~2-way conflicts (free).
// ---------------------------------------------------------------------------
__global__ __launch_bounds__(256) void k_parent(
    const float* __restrict__ x, const float* __restrict__ pW,
    const float* __restrict__ pb, float* __restrict__ pout,
    int* __restrict__ pc) {
  __shared__ float smem[BK * BM + BK * P_];   // 6144 floats = 24 KB
  float* xT = smem;               // [BK][64] swizzled
  float* wT = smem + BK * BM;     // [BK][64] swizzled

  const int tid = threadIdx.x;
  const int b0  = blockIdx.x * BM;
  const int q   = tid & 15;        // d-quad for staging: d = 4q+i
  const int rw  = tid >> 4;        // 0..15: staging rows rw+16j
  const int tc4 = (tid & 15) << 2; // compute: parent base
  const int tr4 = (tid >> 4) << 2; // compute: row base

  const float* xg = x + (size_t)b0 * D_;

  float4 xa[4], wb[4];
#pragma unroll
  for (int j = 0; j < 4; ++j) {
    xa[j] = *(const float4*)&xg[(size_t)(rw + 16 * j) * D_ + (q << 2)];
    wb[j] = *(const float4*)&pW[(size_t)(rw + 16 * j) * D_ + (q << 2)];
  }

  float acc[4][4];
#pragma unroll
  for (int i = 0; i < 4; ++i)
#pragma unroll
    for (int jj = 0; jj < 4; ++jj) acc[i][jj] = 0.f;

  const int swz = q << 2;  // write-side XOR: 4*(d>>2) with d = 4q+i
  for (int kk = 0; kk < NCH; ++kk) {
    // stage regs -> LDS (transpose, swizzled)
#pragma unroll
    for (int j = 0; j < 4; ++j) {
      const int cx = (rw + 16 * j) ^ swz;
      xT[(4 * q + 0) * BM + cx] = xa[j].x;
      xT[(4 * q + 1) * BM + cx] = xa[j].y;
      xT[(4 * q + 2) * BM + cx] = xa[j].z;
      xT[(4 * q + 3) * BM + cx] = xa[j].w;
      wT[(4 * q + 0) * P_ + cx] = wb[j].x;
      wT[(4 * q + 1) * P_ + cx] = wb[j].y;
      wT[(4 * q + 2) * P_ + cx] = wb[j].z;
      wT[(4 * q + 3) * P_ + cx] = wb[j].w;
    }
    __syncthreads();
    // prefetch next chunk into regs; vmcnt waits land at next stage()
    if (kk + 1 < NCH) {
      const int d0 = (kk + 1) * BK;
#pragma unroll
      for (int j = 0; j < 4; ++j) {
        xa[j] = *(const float4*)&xg[(size_t)(rw + 16 * j) * D_ + d0 + (q << 2)];
        wb[j] = *(const float4*)&pW[(size_t)(rw + 16 * j) * D_ + d0 + (q << 2)];
      }
    }
#pragma unroll 8
    for (int d = 0; d < BK; ++d) {
      const int sz = ((d >> 2) & 15) << 2;
      const float4 xv = *(const float4*)&xT[d * BM + (tr4 ^ sz)];
      const float4 wv = *(const float4*)&wT[d * P_ + (tc4 ^ sz)];
      acc[0][0] += xv.x * wv.x; acc[0][1] += xv.x * wv.y;
      acc[0][2] += xv.x * wv.z; acc[0][3] += xv.x * wv.w;
      acc[1][0] += xv.y * wv.x; acc[1][1] += xv.y * wv.y;
      acc[1][2] += xv.y * wv.z; acc[1][3] += xv.y * wv.w;
      acc[2][0] += xv.z * wv.x; acc[2][1] += xv.z * wv.y;
      acc[2][2] += xv.z * wv.z; acc[2][3] += xv.z * wv.w;
      acc[3][0] += xv.w * wv.x; acc[3][1] += xv.w * wv.y;
      acc[3][2] += xv.w * wv.z; acc[3][3] += xv.w * wv.w;
    }
    __syncthreads();
  }

  // epilogue: +bias, store logits, argmax via reused LDS
  const float4 bias = *(const float4*)&pb[tc4];
  float* pl = smem;  // [64][68] = 4352 floats <= 6144, safe after last barrier
#pragma unroll
  for (int ri = 0; ri < 4; ++ri) {
    const int r = tr4 + ri;
    float4 v;
    v.x = acc[ri][0] + bias.x; v.y = acc[ri][1] + bias.y;
    v.z = acc[ri][2] + bias.z; v.w = acc[ri][3] + bias.w;
    *(float4*)&pout[(size_t)(b0 + r) * P_ + tc4] = v;
    *(float4*)&pl[r * 68 + tc4] = v;
  }
  __syncthreads();
  if (tid < BM) {
    const int r = tid;
    float best = pl[r * 68];
    int arg = 0;
#pragma unroll
    for (int p = 1; p < P_; ++p) {
      const float v = pl[r * 68 + p];
      if (v > best) { best = v; arg = p; }  // strict > keeps first index (jnp.argmax)
    }
    pc[b0 + r] = arg;
  }
}

// ---------------------------------------------------------------------------
// Kernel 2: child logits. One block per (expert e, 1024-row chunk). Stage W_e
// (5x2048 fp32 = 40 KB) in LDS once; scan pc[] for rows of this expert; each
// wave processes its matching rows with lane-split-D dot products + shfl
// reduction. child_W L2 traffic: 1024 blocks x 40 KB = 40 MB (vs 655 MB if
// fetched per-row). x rows come from L3 (resident after K1).
// ---------------------------------------------------------------------------
__global__ __launch_bounds__(256) void k_child(
    const float* __restrict__ x, const float* __restrict__ cW,
    const float* __restrict__ cb, const int* __restrict__ pc,
    float* __restrict__ cout) {
  __shared__ float wlds[K_ * D_];  // 40 KB
  const int e = blockIdx.x >> 4;   // expert
  const int m = blockIdx.x & 15;   // row chunk
  const int tid = threadIdx.x;

  const float4* wg4 = (const float4*)(cW + (size_t)e * K_ * D_);
  float4* wl4 = (float4*)wlds;
#pragma unroll
  for (int t = 0; t < 10; ++t) wl4[tid + 256 * t] = wg4[tid + 256 * t];
  __syncthreads();

  const int wave = tid >> 6;
  const int lane = tid & 63;
  const float bk0 = cb[e * K_ + 0], bk1 = cb[e * K_ + 1], bk2 = cb[e * K_ + 2],
              bk3 = cb[e * K_ + 3], bk4 = cb[e * K_ + 4];

  const int rbase0 = m * 1024 + wave * 256;
  for (int it = 0; it < 4; ++it) {
    const int rb = rbase0 + it * 64;
    const int myc = pc[rb + lane];
    unsigned long long mask = __ballot(myc == e);
    while (mask) {
      const int bit = __ffsll(mask) - 1;
      mask &= mask - 1;
      const int r = rb + bit;
      const float4* xr4 = (const float4*)(x + (size_t)r * D_);
      float a0 = 0.f, a1 = 0.f, a2 = 0.f, a3 = 0.f, a4 = 0.f;
#pragma unroll
      for (int t = 0; t < 8; ++t) {
        const float4 xv = xr4[lane + 64 * t];
        const float4 w0 = wl4[lane + 64 * t];
        const float4 w1 = wl4[512 + lane + 64 * t];
        const float4 w2 = wl4[1024 + lane + 64 * t];
        const float4 w3 = wl4[1536 + lane + 64 * t];
        const float4 w4 = wl4[2048 + lane + 64 * t];
        a0 += xv.x * w0.x + xv.y * w0.y + xv.z * w0.z + xv.w * w0.w;
        a1 += xv.x * w1.x + xv.y * w1.y + xv.z * w1.z + xv.w * w1.w;
        a2 += xv.x * w2.x + xv.y * w2.y + xv.z * w2.z + xv.w * w2.w;
        a3 += xv.x * w3.x + xv.y * w3.y + xv.z * w3.z + xv.w * w3.w;
        a4 += xv.x * w4.x + xv.y * w4.y + xv.z * w4.z + xv.w * w4.w;
      }
#pragma unroll
      for (int s = 32; s > 0; s >>= 1) {
        a0 += __shfl_xor(a0, s, 64);
        a1 += __shfl_xor(a1, s, 64);
        a2 += __shfl_xor(a2, s, 64);
        a3 += __shfl_xor(a3, s, 64);
        a4 += __shfl_xor(a4, s, 64);
      }
      if (lane == 0) {
        float* o = cout + (size_t)r * K_;
        o[0] = a0 + bk0; o[1] = a1 + bk1; o[2] = a2 + bk2;
        o[3] = a3 + bk3; o[4] = a4 + bk4;
      }
    }
  }
}

extern "C" void kernel_launch(void* const* d_in, const int* in_sizes, int n_in,
                              void* d_out, int out_size, void* d_ws, size_t ws_size,
                              hipStream_t stream) {
  const float* x  = (const float*)d_in[0];
  const float* pW = (const float*)d_in[1];
  const float* pb = (const float*)d_in[2];
  const float* cW = (const float*)d_in[3];
  const float* cb = (const float*)d_in[4];
  float* pout = (float*)d_out;                       // [B, 64]
  float* cout = (float*)d_out + (size_t)B_ * P_;     // [B, 5]
  int* pc = (int*)d_ws;                              // 64 KB of workspace

  k_parent<<<B_ / BM, 256, 0, stream>>>(x, pW, pb, pout, pc);
  k_child<<<P_ * 16, 256, 0, stream>>>(x, cW, cb, pc, cout);
}